// Round 9
// baseline (378.194 us; speedup 1.0000x reference)
//
#include <hip/hip_runtime.h>

#define N_NODES 50000
#define N_EDGES 800000
#define D 128
#define MAXDEG 64    // Poisson(16) max deg over 50k nodes ~45; slots clamped
#define NBUCK 196    // coarse bucket = dst>>8 (256 nodes/bucket)
#define BUCKCAP 5120 // expected 4096/bucket, +16 sigma
#define EPB 4096     // edges per bucket-sort block
#define NBB 196      // ceil(800000/4096)
#define NB2 392      // CSR-build virtual blocks: 128 nodes each
#define GB 782       // gemm virtual blocks, 64 rows each
#define FBV 3125     // gather virtual blocks, 16 nodes each
#define SP 136       // padded LDS row stride (ushorts)

typedef __attribute__((ext_vector_type(8))) short bf16x8;
typedef __attribute__((ext_vector_type(4))) float f32x4;

// ---------------------------------------------------------------------------
__device__ inline unsigned short f2bf(float f) {  // round-to-nearest-even
    unsigned u = __float_as_uint(f);
    unsigned r = (u + 0x7fffu + ((u >> 16) & 1u)) >> 16;
    return (unsigned short)r;
}

// ---------------------------------------------------------------------------
// Device-wide barrier for a fully-resident grid (persistent-kernel pattern).
// bar[0]=arrive counter, bar[1]=generation; zeroed by k_prep. Agent-scope
// atomics + threadfence per CDNA Guideline 16 (cross-XCD visibility).
// Grid is sized via occupancy query so ALL blocks are co-resident.
__device__ inline void grid_sync(int* bar) {
    __syncthreads();
    if (threadIdx.x == 0) {
        __threadfence();  // release this block's writes device-wide
        int gen = __hip_atomic_load(bar + 1, __ATOMIC_RELAXED,
                                    __HIP_MEMORY_SCOPE_AGENT);
        int a = __hip_atomic_fetch_add(bar, 1, __ATOMIC_ACQ_REL,
                                       __HIP_MEMORY_SCOPE_AGENT);
        if (a == (int)gridDim.x - 1) {
            __hip_atomic_store(bar, 0, __ATOMIC_RELAXED,
                               __HIP_MEMORY_SCOPE_AGENT);
            __hip_atomic_fetch_add(bar + 1, 1, __ATOMIC_RELEASE,
                                   __HIP_MEMORY_SCOPE_AGENT);
        } else {
            while (__hip_atomic_load(bar + 1, __ATOMIC_RELAXED,
                                     __HIP_MEMORY_SCOPE_AGENT) == gen)
                __builtin_amdgcn_s_sleep(2);
        }
        __threadfence();  // acquire other blocks' writes
    }
    __syncthreads();
}

// ---------------------------------------------------------------------------
// Prologue: blocks 0,1 transpose W1/W2 to bf16 n-major; block 2 zeroes
// {cursor, barrier} (replaces the memset dispatch).
__global__ __launch_bounds__(256) void k_prep(const float* __restrict__ W1,
                                              const float* __restrict__ W2,
                                              unsigned short* __restrict__ Wt1,
                                              unsigned short* __restrict__ Wt2,
                                              int* __restrict__ zbase, int nz) {
    int tid = threadIdx.x;
    if (blockIdx.x < 2) {
        const float* W = (blockIdx.x == 0) ? W1 : W2;
        unsigned short* Wt = (blockIdx.x == 0) ? Wt1 : Wt2;
        for (int idx = tid; idx < D * D; idx += 256) {
            int n = idx & 127, k = idx >> 7;
            Wt[n * D + k] = f2bf(W[k * D + n]);
        }
        return;
    }
    for (int i = tid; i < nz; i += 256) zbase[i] = 0;
}

// ---------------------------------------------------------------------------
struct GArgs {
    const int* src; const int* dst; const float* ew;
    const float* X; const float* b1; const float* b2;
    const unsigned short* Wt1; const unsigned short* Wt2;
    int* cursor; int* bar;
    uint2* buck; unsigned* csr; int* cnt; float* dinv;
    unsigned short* h0; unsigned short* hb;
    float* out;
};

// ---------------------------------------------------------------------------
// Persistent mega-kernel. Phases (device-wide barrier between each):
//  P1: bucket sort (vb<196) || layer-1 GEMM h0=bf16(x@W1) (vb 196..977)
//      -- GEMM depends only on Wt1, so it hides under the sort now.
//  P2: CSR build, 128 nodes/virtual-block (r8 proven body).
//  P3: agg1+relu+bias then @W2 MFMA -> hb (r8 proven body).
//  P4: layer-2 aggregate -> fp32 out (r8 proven body).
// All bodies are the r8-verified kernels, re-indexed by virtual block.
__global__ __launch_bounds__(256) void k_mega(GArgs a) {
    __shared__ union SM {
        struct {                             // P1 sort: ~35.7 KB
            uint2 sorted[EPB];
            int hist[NBUCK];
            int scn[NBUCK];
            int gbase[NBUCK];
            int s[256];
        } so;
        struct {                             // P2 build: ~33 KB
            unsigned csr_loc[128 * MAXDEG];
            int cnt_loc[128];
            int deg_loc[128];
        } b;
        unsigned short sX[64 * D];           // P1 gemm: 16 KB
        unsigned short sT[16 * SP];          // P3: 4.25 KB
    } sm;
    int tid = threadIdx.x;

    // ======================= P1: sort || gemm ============================
    for (int vb = blockIdx.x; vb < NBB + GB; vb += gridDim.x) {
        if (vb < NBB) {  // ----- bucket sort (r2/r8 proven 256-thr body) ---
            int e0 = vb * EPB;
            for (int i = tid; i < NBUCK; i += 256) sm.so.hist[i] = 0;
            __syncthreads();
            #pragma unroll
            for (int j = 0; j < 16; ++j) {
                int e = e0 + j * 256 + tid;
                if (e < N_EDGES) atomicAdd(&sm.so.hist[a.dst[e] >> 8], 1);
            }
            __syncthreads();
            int v = tid < NBUCK ? sm.so.hist[tid] : 0;
            sm.so.s[tid] = v;
            __syncthreads();
            for (int off = 1; off < 256; off <<= 1) {
                int u = tid >= off ? sm.so.s[tid - off] : 0;
                __syncthreads();
                sm.so.s[tid] += u;
                __syncthreads();
            }
            int excl = sm.so.s[tid] - v;
            if (tid < NBUCK) {
                sm.so.scn[tid] = excl;
                sm.so.gbase[tid] = v ? atomicAdd(&a.cursor[tid], v) : 0;
                sm.so.hist[tid] = excl;  // running scatter cursor
            }
            __syncthreads();
            #pragma unroll
            for (int j = 0; j < 16; ++j) {
                int e = e0 + j * 256 + tid;
                if (e < N_EDGES) {
                    int d = a.dst[e];
                    int sv = a.src[e];
                    unsigned wf = min(__float2uint_rn(a.ew[e] * 65536.f), 65535u);
                    int slot = atomicAdd(&sm.so.hist[d >> 8], 1);
                    sm.so.sorted[slot] =
                        make_uint2(((unsigned)sv << 16) | wf, (unsigned)d);
                }
            }
            __syncthreads();
            int total = min(EPB, N_EDGES - e0);
            for (int i = tid; i < total; i += 256) {
                uint2 en = sm.so.sorted[i];
                int bk = (int)(en.y >> 8);
                int g = sm.so.gbase[bk] + (i - sm.so.scn[bk]);
                if (g < BUCKCAP)
                    a.buck[(size_t)bk * BUCKCAP + g] =
                        make_uint2(en.x, en.y & 255u);
            }
        } else {  // ----- layer-1 GEMM (r8 proven body) -----
            int row0 = (vb - NBB) * 64;
            int nr = min(64, N_NODES - row0);
            {
                const float4* xs = (const float4*)(a.X + (size_t)row0 * D);
                int nvec = nr * (D / 4);
                for (int i = tid; i < nvec; i += 256) {
                    float4 v = xs[i];
                    ushort4 o;
                    o.x = f2bf(v.x); o.y = f2bf(v.y);
                    o.z = f2bf(v.z); o.w = f2bf(v.w);
                    *(ushort4*)(sm.sX + i * 4) = o;
                }
            }
            __syncthreads();
            int wave = tid >> 6, lane = tid & 63;
            int m = lane & 15, quad = lane >> 4;
            f32x4 acc[8];
            #pragma unroll
            for (int i = 0; i < 8; ++i) acc[i] = (f32x4){0.f, 0.f, 0.f, 0.f};
            const unsigned short* aBase = sm.sX + (wave * 16 + m) * D + quad * 8;
            #pragma unroll
            for (int c = 0; c < 4; ++c) {
                bf16x8 av = *(const bf16x8*)(aBase + c * 32);
                #pragma unroll
                for (int n0 = 0; n0 < 8; ++n0) {
                    bf16x8 bv = *(const bf16x8*)(a.Wt1 + (n0 * 16 + m) * D +
                                                 c * 32 + quad * 8);
                    acc[n0] = __builtin_amdgcn_mfma_f32_16x16x32_bf16(
                        av, bv, acc[n0], 0, 0, 0);
                }
            }
            unsigned short* sOut = sm.sX + wave * 16 * D;
            __syncthreads();
            #pragma unroll
            for (int n0 = 0; n0 < 8; ++n0)
                #pragma unroll
                for (int i = 0; i < 4; ++i)
                    sOut[(quad * 4 + i) * D + n0 * 16 + m] = f2bf(acc[n0][i]);
            __syncthreads();
            int rr = lane >> 2, c0 = (lane & 3) * 32;
            int grow = row0 + wave * 16 + rr;
            if (grow < N_NODES) {
                uint4* dstp = (uint4*)(a.h0 + (size_t)grow * D + c0);
                const uint4* srcp = (const uint4*)(sOut + rr * D + c0);
                dstp[0] = srcp[0]; dstp[1] = srcp[1];
                dstp[2] = srcp[2]; dstp[3] = srcp[3];
            }
        }
    }
    grid_sync(a.bar);

    // ======================= P2: CSR build ===============================
    for (int vb = blockIdx.x; vb < NB2; vb += gridDim.x) {
        __syncthreads();  // LDS reuse safety across iterations/phases
        int bucket = vb >> 1;
        unsigned hbit = (unsigned)(vb & 1) << 7;
        if (tid < 128) {
            sm.b.cnt_loc[tid] = 0;
            sm.b.deg_loc[tid] = 0;
        }
        {
            uint4* z4 = (uint4*)sm.b.csr_loc;
            #pragma unroll
            for (int i = 0; i < (128 * MAXDEG / 4) / 256; ++i)
                z4[i * 256 + tid] = make_uint4(0u, 0u, 0u, 0u);
        }
        __syncthreads();
        int n = min(a.cursor[bucket], BUCKCAP);
        const uint2* bb = a.buck + (size_t)bucket * BUCKCAP;
        for (int i = tid; i < n; i += 256) {
            uint2 e = bb[i];
            if ((e.y & 128u) == hbit) {
                int ln = (int)(e.y & 127u);
                int slot = atomicAdd(&sm.b.cnt_loc[ln], 1);
                if (slot < MAXDEG) sm.b.csr_loc[ln * MAXDEG + slot] = e.x;
                atomicAdd(&sm.b.deg_loc[ln], (int)(e.x & 0xffffu));
            }
        }
        __syncthreads();
        int node0 = vb * 128;
        int nnodes = min(128, N_NODES - node0);
        if (nnodes > 0) {
            uint4* g = (uint4*)(a.csr + (size_t)node0 * MAXDEG);
            const uint4* l = (const uint4*)sm.b.csr_loc;
            int nv = nnodes * (MAXDEG / 4);
            for (int i = tid; i < nv; i += 256) g[i] = l[i];
            if (tid < nnodes) {
                int node = node0 + tid;
                a.cnt[node] = min(sm.b.cnt_loc[tid], MAXDEG);
                float sum = (float)sm.b.deg_loc[tid] * (1.f / 65536.f);
                a.dinv[node] = sum > 0.f ? rsqrtf(fmaxf(sum, 1e-30f)) : 0.f;
            }
        }
    }
    grid_sync(a.bar);

    // ======================= P3: agg1 + @W2 MFMA =========================
    for (int vb = blockIdx.x; vb < FBV; vb += gridDim.x) {
        __syncthreads();  // sT reuse safety across iterations
        int wave = tid >> 6, lane = tid & 63;
        int g = lane >> 4, fl = lane & 15;
        int nb = vb * 16;
        int node = nb + wave * 4 + g;
        int end = min(a.cnt[node], MAXDEG);
        const uint4* row4 = (const uint4*)(a.csr + (size_t)node * MAXDEG);
        float acc[8] = {0.f, 0.f, 0.f, 0.f, 0.f, 0.f, 0.f, 0.f};
        for (int b0 = 0; b0 < end; b0 += 8) {
            uint4 ca = row4[(b0 >> 2)];
            uint4 cb = row4[(b0 >> 2) + 1];
            unsigned cs[8] = {ca.x, ca.y, ca.z, ca.w, cb.x, cb.y, cb.z, cb.w};
            uint4 u[8];
            float nmv[8];
            #pragma unroll
            for (int j = 0; j < 8; ++j) {
                unsigned sv = cs[j] >> 16;
                u[j] = *(const uint4*)(a.h0 + (size_t)sv * D + fl * 8);
                nmv[j] = (float)(cs[j] & 0xffffu) * (1.f / 65536.f)
                         * a.dinv[sv];
            }
            #pragma unroll
            for (int j = 0; j < 8; ++j) {
                unsigned a0[4] = {u[j].x, u[j].y, u[j].z, u[j].w};
                #pragma unroll
                for (int q = 0; q < 4; ++q) {
                    acc[2 * q]     += __uint_as_float(a0[q] << 16) * nmv[j];
                    acc[2 * q + 1] += __uint_as_float(a0[q] & 0xffff0000u) * nmv[j];
                }
            }
        }
        {
            float dn = a.dinv[node];
            int f = fl * 8;
            float4 bv0 = *(const float4*)(a.b1 + f);
            float4 bv1 = *(const float4*)(a.b1 + f + 4);
            ushort4 o0, o1;
            o0.x = f2bf(fmaxf(acc[0] * dn + bv0.x, 0.f));
            o0.y = f2bf(fmaxf(acc[1] * dn + bv0.y, 0.f));
            o0.z = f2bf(fmaxf(acc[2] * dn + bv0.z, 0.f));
            o0.w = f2bf(fmaxf(acc[3] * dn + bv0.w, 0.f));
            o1.x = f2bf(fmaxf(acc[4] * dn + bv1.x, 0.f));
            o1.y = f2bf(fmaxf(acc[5] * dn + bv1.y, 0.f));
            o1.z = f2bf(fmaxf(acc[6] * dn + bv1.z, 0.f));
            o1.w = f2bf(fmaxf(acc[7] * dn + bv1.w, 0.f));
            unsigned short* tp = sm.sT + (wave * 4 + g) * SP + f;
            *(ushort4*)(tp) = o0;
            *(ushort4*)(tp + 4) = o1;
        }
        __syncthreads();
        int m = lane & 15, quad = lane >> 4;
        f32x4 acc2[2];
        acc2[0] = (f32x4){0.f, 0.f, 0.f, 0.f};
        acc2[1] = (f32x4){0.f, 0.f, 0.f, 0.f};
        #pragma unroll
        for (int c = 0; c < 4; ++c) {
            bf16x8 av = *(const bf16x8*)(sm.sT + m * SP + c * 32 + quad * 8);
            #pragma unroll
            for (int t = 0; t < 2; ++t) {
                int n0 = wave * 2 + t;
                bf16x8 bv = *(const bf16x8*)(a.Wt2 + (n0 * 16 + m) * D +
                                             c * 32 + quad * 8);
                acc2[t] = __builtin_amdgcn_mfma_f32_16x16x32_bf16(
                    av, bv, acc2[t], 0, 0, 0);
            }
        }
        float dv[4];
        #pragma unroll
        for (int i = 0; i < 4; ++i) dv[i] = a.dinv[nb + quad * 4 + i];
        __syncthreads();
        #pragma unroll
        for (int t = 0; t < 2; ++t)
            #pragma unroll
            for (int i = 0; i < 4; ++i)
                sm.sT[(quad * 4 + i) * SP + (wave * 2 + t) * 16 + m] =
                    f2bf(acc2[t][i] * dv[i]);
        __syncthreads();
        int rr = tid >> 4, cc = (tid & 15) * 8;
        *(uint4*)(a.hb + (size_t)(nb + rr) * D + cc) =
            *(const uint4*)(sm.sT + rr * SP + cc);
    }
    grid_sync(a.bar);

    // ======================= P4: layer-2 aggregate =======================
    for (int vb = blockIdx.x; vb < FBV; vb += gridDim.x) {
        int wave = tid >> 6, lane = tid & 63;
        int g = lane >> 4, fl = lane & 15;
        int node = vb * 16 + wave * 4 + g;
        int end = min(a.cnt[node], MAXDEG);
        const uint4* row4 = (const uint4*)(a.csr + (size_t)node * MAXDEG);
        float acc[8] = {0.f, 0.f, 0.f, 0.f, 0.f, 0.f, 0.f, 0.f};
        for (int b0 = 0; b0 < end; b0 += 8) {
            uint4 ca = row4[(b0 >> 2)];
            uint4 cb = row4[(b0 >> 2) + 1];
            unsigned cs[8] = {ca.x, ca.y, ca.z, ca.w, cb.x, cb.y, cb.z, cb.w};
            uint4 u[8];
            float nmv[8];
            #pragma unroll
            for (int j = 0; j < 8; ++j) {
                unsigned sv = cs[j] >> 16;
                u[j] = *(const uint4*)(a.hb + (size_t)sv * D + fl * 8);
                nmv[j] = (float)(cs[j] & 0xffffu) * (1.f / 65536.f);
            }
            #pragma unroll
            for (int j = 0; j < 8; ++j) {
                unsigned a0[4] = {u[j].x, u[j].y, u[j].z, u[j].w};
                #pragma unroll
                for (int q = 0; q < 4; ++q) {
                    acc[2 * q]     += __uint_as_float(a0[q] << 16) * nmv[j];
                    acc[2 * q + 1] += __uint_as_float(a0[q] & 0xffff0000u) * nmv[j];
                }
            }
        }
        float dn = a.dinv[node];
        int f = fl * 8;
        float4 bv0 = *(const float4*)(a.b2 + f);
        float4 bv1 = *(const float4*)(a.b2 + f + 4);
        float* op = a.out + (size_t)node * D + f;
        *(float4*)(op) = make_float4(acc[0] * dn + bv0.x, acc[1] * dn + bv0.y,
                                     acc[2] * dn + bv0.z, acc[3] * dn + bv0.w);
        *(float4*)(op + 4) = make_float4(acc[4] * dn + bv1.x, acc[5] * dn + bv1.y,
                                         acc[6] * dn + bv1.z, acc[7] * dn + bv1.w);
    }
}

// ---------------------------------------------------------------------------
extern "C" void kernel_launch(void* const* d_in, const int* in_sizes, int n_in,
                              void* d_out, int out_size, void* d_ws, size_t ws_size,
                              hipStream_t stream) {
    const float* x   = (const float*)d_in[0];
    const int*   ei  = (const int*)d_in[1];   // [2, E] int32
    const float* ew  = (const float*)d_in[2];
    const float* W1  = (const float*)d_in[3];
    const float* b1  = (const float*)d_in[4];
    const float* W2  = (const float*)d_in[5];
    const float* b2  = (const float*)d_in[6];
    float* out = (float*)d_out;

    const int* src = ei;
    const int* dst = ei + N_EDGES;

    char* base = (char*)d_ws;
    size_t off = 0;
    auto take = [&](size_t bytes) -> char* {
        char* p = base + off;
        off += (bytes + 255) & ~(size_t)255;
        return p;
    };
    int*      cursor = (int*)take(NBUCK * 4);
    int*      bar    = (int*)take(8);
    size_t zero_bytes = off;  // cursor + barrier words
    float*    dinv = (float*)take(N_NODES * 4);
    int*      cnt  = (int*)take(N_NODES * 4);
    uint2*    buck = (uint2*)take((size_t)NBUCK * BUCKCAP * 8);            // 8.0 MB
    unsigned* csr  = (unsigned*)take((size_t)N_NODES * MAXDEG * 4);        // 12.8 MB
    unsigned short* Wt1 = (unsigned short*)take(D * D * 2);
    unsigned short* Wt2 = (unsigned short*)take(D * D * 2);
    unsigned short* h0  = (unsigned short*)take((size_t)N_NODES * D * 2);  // raw x@W1
    unsigned short* hb  = (unsigned short*)take((size_t)N_NODES * D * 2);  // layer-2 H'

    // grid sized so ALL blocks are co-resident (hand-rolled grid barrier).
    // LDS union = ~36 KB -> at most 4 blocks/CU; clamp defensively.
    int per_cu = 0;
    (void)hipOccupancyMaxActiveBlocksPerMultiprocessor(&per_cu, k_mega, 256, 0);
    if (per_cu < 1) per_cu = 1;
    if (per_cu > 4) per_cu = 4;
    int grid = per_cu * 256;   // 256 CUs on MI355X

    // prologue: W transposes + zero {cursor, barrier}
    k_prep<<<3, 256, 0, stream>>>(W1, W2, Wt1, Wt2,
                                  (int*)d_ws, (int)(zero_bytes / 4));

    GArgs args;
    args.src = src; args.dst = dst; args.ew = ew;
    args.X = x; args.b1 = b1; args.b2 = b2;
    args.Wt1 = Wt1; args.Wt2 = Wt2;
    args.cursor = cursor; args.bar = bar;
    args.buck = buck; args.csr = csr; args.cnt = cnt; args.dinv = dinv;
    args.h0 = h0; args.hb = hb; args.out = out;

    // persistent fused pipeline: [sort || gemm] -> build -> agg_mm -> aggregate
    k_mega<<<grid, 256, 0, stream>>>(args);
}

// Round 10
// 193.233 us; speedup vs baseline: 1.9572x; 1.9572x over previous
//
#include <hip/hip_runtime.h>

#define N_NODES 50000
#define N_EDGES 800000
#define D 128
#define MAXDEG 64    // Poisson(16) max deg over 50k nodes ~45; slots clamped
#define NBUCK 196    // coarse bucket = dst>>8 (256 nodes/bucket)
#define BUCKCAP 5120 // expected 4096/bucket, +16 sigma
#define EPB 4096     // edges per bucket-sort block
#define NBB 196      // ceil(800000/4096)
#define BTH 512      // k_bucket block size
#define GB 782       // gemm blocks, 64 rows each
#define SP 136       // padded LDS row stride (ushorts): 272B = 68 dwords, %32=4

typedef __attribute__((ext_vector_type(8))) short bf16x8;
typedef __attribute__((ext_vector_type(4))) float f32x4;

// ---------------------------------------------------------------------------
__device__ inline unsigned short f2bf(float f) {  // round-to-nearest-even
    unsigned u = __float_as_uint(f);
    unsigned r = (u + 0x7fffu + ((u >> 16) & 1u)) >> 16;
    return (unsigned short)r;
}

// ---------------------------------------------------------------------------
// Pass 1: LDS counting-sort per 4096-edge block, contiguous per-bucket runs.
// 512 threads/block. Blocks [NBB, NBB+2) transpose W1/W2 to bf16 n-major.
__global__ __launch_bounds__(BTH) void k_bucket(const int* __restrict__ src,
                                                const int* __restrict__ dst,
                                                const float* __restrict__ ew,
                                                int* __restrict__ cursor,
                                                uint2* __restrict__ buck,
                                                const float* __restrict__ W1,
                                                const float* __restrict__ W2,
                                                unsigned short* __restrict__ Wt1,
                                                unsigned short* __restrict__ Wt2) {
    if (blockIdx.x >= NBB) {
        const float* W = (blockIdx.x == NBB) ? W1 : W2;
        unsigned short* Wt = (blockIdx.x == NBB) ? Wt1 : Wt2;
        for (int idx = threadIdx.x; idx < D * D; idx += BTH) {
            int n = idx & 127, k = idx >> 7;
            Wt[n * D + k] = f2bf(W[k * D + n]);
        }
        return;
    }
    __shared__ uint2 sorted[EPB];   // 32 KB
    __shared__ int hist[NBUCK];     // counts, then running scatter cursor
    __shared__ int scn[NBUCK];      // exclusive scan (preserved)
    __shared__ int gbase[NBUCK];
    __shared__ int s[256];
    int tid = threadIdx.x;
    int e0 = blockIdx.x * EPB;
    for (int i = tid; i < NBUCK; i += BTH) hist[i] = 0;
    __syncthreads();
    #pragma unroll
    for (int j = 0; j < EPB / BTH; ++j) {   // 8 rounds
        int e = e0 + j * BTH + tid;
        if (e < N_EDGES) atomicAdd(&hist[dst[e] >> 8], 1);
    }
    __syncthreads();
    // scan over 256 slots on the first 256 lanes; all threads hit barriers
    int v = 0;
    if (tid < 256) {
        v = tid < NBUCK ? hist[tid] : 0;
        s[tid] = v;
    }
    __syncthreads();
    for (int off = 1; off < 256; off <<= 1) {
        int u = 0;
        if (tid < 256 && tid >= off) u = s[tid - off];
        __syncthreads();
        if (tid < 256) s[tid] += u;
        __syncthreads();
    }
    if (tid < NBUCK) {
        int excl = s[tid] - v;
        scn[tid] = excl;
        gbase[tid] = v ? atomicAdd(&cursor[tid], v) : 0;
        hist[tid] = excl;  // becomes running scatter cursor
    }
    __syncthreads();
    #pragma unroll
    for (int j = 0; j < EPB / BTH; ++j) {   // 8 rounds
        int e = e0 + j * BTH + tid;
        if (e < N_EDGES) {
            int d = dst[e];
            int sv = src[e];
            unsigned wf = min(__float2uint_rn(ew[e] * 65536.f), 65535u);
            int slot = atomicAdd(&hist[d >> 8], 1);
            sorted[slot] = make_uint2(((unsigned)sv << 16) | wf, (unsigned)d);
        }
    }
    __syncthreads();
    int total = min(EPB, N_EDGES - e0);
    for (int i = tid; i < total; i += BTH) {
        uint2 en = sorted[i];
        int bk = (int)(en.y >> 8);
        int g = gbase[bk] + (i - scn[bk]);
        if (g < BUCKCAP)
            buck[(size_t)bk * BUCKCAP + g] = make_uint2(en.x, en.y & 255u);
    }
}

// ---------------------------------------------------------------------------
// Fused pass 2 + layer-1 GEMM (round-2 proven structure):
//  blocks [0,NBUCK): CSR build (LDS-atomic slotting, dense write-out, LDS deg)
//  blocks [NBUCK, NBUCK+GB): h0 = bf16(x @ W1)  -- dinv UN-folded
// LDS is a 66 KB union -> 2 blocks/CU for both roles.
// csr_loc ZERO-FILLED -> padded slots are (sv=0, w=0) benign no-op edges.
__global__ __launch_bounds__(256) void k_build_gemm(
        const int* __restrict__ cursor, const uint2* __restrict__ buck,
        unsigned* __restrict__ csr, int* __restrict__ cnt,
        float* __restrict__ dinv,
        const float* __restrict__ X, const unsigned short* __restrict__ Wt1,
        unsigned short* __restrict__ h0) {
    __shared__ union SM {
        struct {
            unsigned csr_loc[256 * MAXDEG];  // 64 KB
            int cnt_loc[256];
            int deg_loc[256];
        } b;
        unsigned short sX[64 * D];           // 16 KB (gemm A tile + C reuse)
    } sm;
    int tid = threadIdx.x;

    if (blockIdx.x < NBUCK) {  // ----- CSR build -----
        int b = blockIdx.x;
        sm.b.cnt_loc[tid] = 0;
        sm.b.deg_loc[tid] = 0;
        {   // zero-fill the slot table (padding must be benign for gathers)
            uint4* z4 = (uint4*)sm.b.csr_loc;
            #pragma unroll
            for (int i = 0; i < (256 * MAXDEG / 4) / 256; ++i)
                z4[i * 256 + tid] = make_uint4(0u, 0u, 0u, 0u);
        }
        __syncthreads();
        int n = min(cursor[b], BUCKCAP);
        const uint2* bb = buck + (size_t)b * BUCKCAP;
        for (int i = tid; i < n; i += 256) {
            uint2 e = bb[i];
            int ln = e.y;
            int slot = atomicAdd(&sm.b.cnt_loc[ln], 1);
            if (slot < MAXDEG) sm.b.csr_loc[ln * MAXDEG + slot] = e.x;
            atomicAdd(&sm.b.deg_loc[ln], (int)(e.x & 0xffffu));
        }
        __syncthreads();
        int node0 = b * 256;
        int nnodes = min(256, N_NODES - node0);  // last bucket: 80 nodes
        uint4* g = (uint4*)(csr + (size_t)node0 * MAXDEG);
        const uint4* l = (const uint4*)sm.b.csr_loc;
        int nv = nnodes * (MAXDEG / 4);
        for (int i = tid; i < nv; i += 256) g[i] = l[i];
        if (tid < nnodes) {
            int node = node0 + tid;
            cnt[node] = min(sm.b.cnt_loc[tid], MAXDEG);
            float sum = (float)sm.b.deg_loc[tid] * (1.f / 65536.f);
            dinv[node] = sum > 0.f ? rsqrtf(fmaxf(sum, 1e-30f)) : 0.f;
        }
        return;
    }

    // ----- layer-1 GEMM (no dinv fold) -----
    int row0 = (blockIdx.x - NBUCK) * 64;
    int nr = min(64, N_NODES - row0);
    {
        const float4* xs = (const float4*)(X + (size_t)row0 * D);
        int nvec = nr * (D / 4);
        for (int i = tid; i < nvec; i += 256) {
            float4 v = xs[i];
            ushort4 o;
            o.x = f2bf(v.x); o.y = f2bf(v.y); o.z = f2bf(v.z); o.w = f2bf(v.w);
            *(ushort4*)(sm.sX + i * 4) = o;
        }
    }
    __syncthreads();

    int wave = tid >> 6, lane = tid & 63;
    int m = lane & 15, quad = lane >> 4;
    f32x4 acc[8];
    #pragma unroll
    for (int i = 0; i < 8; ++i) acc[i] = (f32x4){0.f, 0.f, 0.f, 0.f};

    const unsigned short* aBase = sm.sX + (wave * 16 + m) * D + quad * 8;
    #pragma unroll
    for (int c = 0; c < 4; ++c) {
        bf16x8 a = *(const bf16x8*)(aBase + c * 32);
        #pragma unroll
        for (int n0 = 0; n0 < 8; ++n0) {
            bf16x8 b = *(const bf16x8*)(Wt1 + (n0 * 16 + m) * D + c * 32 + quad * 8);
            acc[n0] = __builtin_amdgcn_mfma_f32_16x16x32_bf16(a, b, acc[n0], 0, 0, 0);
        }
    }

    unsigned short* sOut = sm.sX + wave * 16 * D;
    __syncthreads();
    #pragma unroll
    for (int n0 = 0; n0 < 8; ++n0)
        #pragma unroll
        for (int i = 0; i < 4; ++i)
            sOut[(quad * 4 + i) * D + n0 * 16 + m] = f2bf(acc[n0][i]);
    __syncthreads();
    int rr = lane >> 2, c0 = (lane & 3) * 32;
    int grow = row0 + wave * 16 + rr;
    if (grow < N_NODES) {
        uint4* dstp = (uint4*)(h0 + (size_t)grow * D + c0);
        const uint4* srcp = (const uint4*)(sOut + rr * D + c0);
        dstp[0] = srcp[0]; dstp[1] = srcp[1]; dstp[2] = srcp[2]; dstp[3] = srcp[3];
    }
}

// ---------------------------------------------------------------------------
// Fused layer-1 aggregate + layer-2 projection (proven body, 8-deep).
// Each 16-lane group owns ONE node; lane fl owns columns fl*8..fl*8+7.
// Edges streamed in batches of 8 unconditional (zero-padded CSR) loads.
__global__ __launch_bounds__(256) void k_agg_mm(const unsigned short* __restrict__ H,
                                                const int* __restrict__ cnt,
                                                const unsigned* __restrict__ csr,
                                                const float* __restrict__ dinv,
                                                const float* __restrict__ b1,
                                                const unsigned short* __restrict__ Wt2,
                                                unsigned short* __restrict__ Hb) {
    __shared__ unsigned short sT[16 * SP];  // 4.25 KB: h1 tile, reused for C
    int tid = threadIdx.x, wave = tid >> 6, lane = tid & 63;
    int g = lane >> 4, fl = lane & 15;
    int nb = blockIdx.x * 16;
    int node = nb + wave * 4 + g;          // group owns this node

    int end = min(cnt[node], MAXDEG);
    const uint4* row4 = (const uint4*)(csr + (size_t)node * MAXDEG);
    float acc[8] = {0.f, 0.f, 0.f, 0.f, 0.f, 0.f, 0.f, 0.f};
    for (int b0 = 0; b0 < end; b0 += 8) {
        uint4 ca = row4[(b0 >> 2)];        // edges b0..b0+3 (broadcast in group)
        uint4 cb = row4[(b0 >> 2) + 1];    // edges b0+4..b0+7
        unsigned cs[8] = {ca.x, ca.y, ca.z, ca.w, cb.x, cb.y, cb.z, cb.w};
        uint4 u[8];
        float nmv[8];
        #pragma unroll
        for (int j = 0; j < 8; ++j) {      // 8 gathers + 8 dinv in flight
            unsigned sv = cs[j] >> 16;
            u[j] = *(const uint4*)(H + (size_t)sv * D + fl * 8);
            nmv[j] = (float)(cs[j] & 0xffffu) * (1.f / 65536.f) * dinv[sv];
        }
        #pragma unroll
        for (int j = 0; j < 8; ++j) {
            unsigned a0[4] = {u[j].x, u[j].y, u[j].z, u[j].w};
            #pragma unroll
            for (int q = 0; q < 4; ++q) {
                acc[2 * q]     += __uint_as_float(a0[q] << 16) * nmv[j];
                acc[2 * q + 1] += __uint_as_float(a0[q] & 0xffff0000u) * nmv[j];
            }
        }
    }
    {   // write relu(dinv*agg + b1) into tile row (padded stride SP)
        float dn = dinv[node];
        int f = fl * 8;
        float4 bv0 = *(const float4*)(b1 + f);
        float4 bv1 = *(const float4*)(b1 + f + 4);
        ushort4 o0, o1;
        o0.x = f2bf(fmaxf(acc[0] * dn + bv0.x, 0.f));
        o0.y = f2bf(fmaxf(acc[1] * dn + bv0.y, 0.f));
        o0.z = f2bf(fmaxf(acc[2] * dn + bv0.z, 0.f));
        o0.w = f2bf(fmaxf(acc[3] * dn + bv0.w, 0.f));
        o1.x = f2bf(fmaxf(acc[4] * dn + bv1.x, 0.f));
        o1.y = f2bf(fmaxf(acc[5] * dn + bv1.y, 0.f));
        o1.z = f2bf(fmaxf(acc[6] * dn + bv1.z, 0.f));
        o1.w = f2bf(fmaxf(acc[7] * dn + bv1.w, 0.f));
        unsigned short* tp = sT + (wave * 4 + g) * SP + f;
        *(ushort4*)(tp) = o0;
        *(ushort4*)(tp + 4) = o1;
    }
    __syncthreads();

    // MFMA projection: A = sT (16 rows, stride SP); wave owns col-tiles 2w,2w+1
    int m = lane & 15, quad = lane >> 4;
    f32x4 acc2[2];
    acc2[0] = (f32x4){0.f, 0.f, 0.f, 0.f};
    acc2[1] = (f32x4){0.f, 0.f, 0.f, 0.f};
    #pragma unroll
    for (int c = 0; c < 4; ++c) {
        bf16x8 a = *(const bf16x8*)(sT + m * SP + c * 32 + quad * 8);
        #pragma unroll
        for (int t = 0; t < 2; ++t) {
            int n0 = wave * 2 + t;
            bf16x8 b = *(const bf16x8*)(Wt2 + (n0 * 16 + m) * D + c * 32 + quad * 8);
            acc2[t] = __builtin_amdgcn_mfma_f32_16x16x32_bf16(a, b, acc2[t], 0, 0, 0);
        }
    }
    float dv[4];
    #pragma unroll
    for (int i = 0; i < 4; ++i) dv[i] = dinv[nb + quad * 4 + i];
    __syncthreads();  // all waves done reading A
    #pragma unroll
    for (int t = 0; t < 2; ++t)
        #pragma unroll
        for (int i = 0; i < 4; ++i)
            sT[(quad * 4 + i) * SP + (wave * 2 + t) * 16 + m] = f2bf(acc2[t][i] * dv[i]);
    __syncthreads();
    int rr = tid >> 4, cc = (tid & 15) * 8;  // 256 thr x 16B = full 16x128 tile
    *(uint4*)(Hb + (size_t)(nb + rr) * D + cc) = *(const uint4*)(sT + rr * SP + cc);
}

// ---------------------------------------------------------------------------
// Final aggregate (layer 2): out[n] = dinv[n] * sum_k w_k * Hb[s_k] + b2 (fp32)
// Same group-owns-node decomposition, 8-deep batches.
__global__ __launch_bounds__(256) void k_aggregate(const unsigned short* __restrict__ H,
                                                   const int* __restrict__ cnt,
                                                   const unsigned* __restrict__ csr,
                                                   const float* __restrict__ dinv,
                                                   const float* __restrict__ bias,
                                                   float* __restrict__ out) {
    int tid = threadIdx.x, wave = tid >> 6, lane = tid & 63;
    int g = lane >> 4, fl = lane & 15;
    int node = blockIdx.x * 16 + wave * 4 + g;

    int end = min(cnt[node], MAXDEG);
    const uint4* row4 = (const uint4*)(csr + (size_t)node * MAXDEG);
    float acc[8] = {0.f, 0.f, 0.f, 0.f, 0.f, 0.f, 0.f, 0.f};
    for (int b0 = 0; b0 < end; b0 += 8) {
        uint4 ca = row4[(b0 >> 2)];
        uint4 cb = row4[(b0 >> 2) + 1];
        unsigned cs[8] = {ca.x, ca.y, ca.z, ca.w, cb.x, cb.y, cb.z, cb.w};
        uint4 u[8];
        float nmv[8];
        #pragma unroll
        for (int j = 0; j < 8; ++j) {
            unsigned sv = cs[j] >> 16;
            u[j] = *(const uint4*)(H + (size_t)sv * D + fl * 8);
            nmv[j] = (float)(cs[j] & 0xffffu) * (1.f / 65536.f);
        }
        #pragma unroll
        for (int j = 0; j < 8; ++j) {
            unsigned a0[4] = {u[j].x, u[j].y, u[j].z, u[j].w};
            #pragma unroll
            for (int q = 0; q < 4; ++q) {
                acc[2 * q]     += __uint_as_float(a0[q] << 16) * nmv[j];
                acc[2 * q + 1] += __uint_as_float(a0[q] & 0xffff0000u) * nmv[j];
            }
        }
    }
    float dn = dinv[node];
    int f = fl * 8;
    float4 bv0 = *(const float4*)(bias + f);
    float4 bv1 = *(const float4*)(bias + f + 4);
    float* op = out + (size_t)node * D + f;
    *(float4*)(op) = make_float4(acc[0] * dn + bv0.x, acc[1] * dn + bv0.y,
                                 acc[2] * dn + bv0.z, acc[3] * dn + bv0.w);
    *(float4*)(op + 4) = make_float4(acc[4] * dn + bv1.x, acc[5] * dn + bv1.y,
                                     acc[6] * dn + bv1.z, acc[7] * dn + bv1.w);
}

// ---------------------------------------------------------------------------
extern "C" void kernel_launch(void* const* d_in, const int* in_sizes, int n_in,
                              void* d_out, int out_size, void* d_ws, size_t ws_size,
                              hipStream_t stream) {
    const float* x   = (const float*)d_in[0];
    const int*   ei  = (const int*)d_in[1];   // [2, E] int32
    const float* ew  = (const float*)d_in[2];
    const float* W1  = (const float*)d_in[3];
    const float* b1  = (const float*)d_in[4];
    const float* W2  = (const float*)d_in[5];
    const float* b2  = (const float*)d_in[6];
    float* out = (float*)d_out;

    const int* src = ei;
    const int* dst = ei + N_EDGES;

    char* base = (char*)d_ws;
    size_t off = 0;
    auto take = [&](size_t bytes) -> char* {
        char* p = base + off;
        off += (bytes + 255) & ~(size_t)255;
        return p;
    };
    int*      cursor = (int*)take(NBUCK * 4);
    size_t zero_bytes = off;  // cursor only
    float*    dinv = (float*)take(N_NODES * 4);
    int*      cnt  = (int*)take(N_NODES * 4);
    uint2*    buck = (uint2*)take((size_t)NBUCK * BUCKCAP * 8);            // 8.0 MB
    unsigned* csr  = (unsigned*)take((size_t)N_NODES * MAXDEG * 4);        // 12.8 MB
    unsigned short* Wt1 = (unsigned short*)take(D * D * 2);
    unsigned short* Wt2 = (unsigned short*)take(D * D * 2);
    unsigned short* h0  = (unsigned short*)take((size_t)N_NODES * D * 2);  // raw x@W1
    unsigned short* hb  = (unsigned short*)take((size_t)N_NODES * D * 2);  // layer-2 H'

    hipMemsetAsync(d_ws, 0, zero_bytes, stream);

    const int FB = N_NODES / 16;            // 3125 (exact)

    // sort edges into coarse buckets (512 threads: 8 serial rounds) + W transposes
    k_bucket<<<NBB + 2, BTH, 0, stream>>>(src, dst, ew, cursor, buck,
                                          W1, W2, Wt1, Wt2);
    // fused: CSR build (blocks 0..195) + layer-1 GEMM (blocks 196..977)
    k_build_gemm<<<NBUCK + GB, 256, 0, stream>>>(cursor, buck, csr, cnt, dinv,
                                                 x, Wt1, h0);
    // fused: agg1 + relu + bias (dinv[src] per edge), then @W2 (MFMA) -> hb
    k_agg_mm<<<FB, 256, 0, stream>>>(h0, cnt, csr, dinv, b1, Wt2, hb);
    // layer 2 aggregate -> fp32 out
    k_aggregate<<<FB, 256, 0, stream>>>(hb, cnt, csr, dinv, b2, out);
}